// Round 3
// baseline (353.274 us; speedup 1.0000x reference)
//
#include <hip/hip_runtime.h>
#include <hip/hip_bf16.h>

typedef __attribute__((ext_vector_type(8))) short bf16x8;
typedef __attribute__((ext_vector_type(4))) float f32x4;

#define B_  512
#define N_  256
#define SD_ 1024
#define HD_ 512
#define AD_ 256

__device__ __forceinline__ unsigned short f2bf(float f) {
    unsigned int u = __float_as_uint(f);
    unsigned int r = (u + 0x7FFFu + ((u >> 16) & 1u)) >> 16;
    return (unsigned short)r;
}

// ---------------------------------------------------------------------------
// K0: pack Wh (AD x HD, f32, row-major) into bf16 B-fragment layout for
// mfma_f32_16x16x32_bf16. Fragment (ct, ks): 64 lanes x 8 bf16 contiguous.
// B[k][col] = Wh[col][k];  col = ct*16 + (lane&15), k = ks*32 + (lane>>4)*8 + i
__global__ void k0_pack(const float* __restrict__ Wh, unsigned short* __restrict__ whp) {
    int g = blockIdx.x * 256 + threadIdx.x;   // 16384 fragment-lanes total
    int ct  = g >> 10;
    int rem = g & 1023;
    int ks  = rem >> 6;
    int l   = rem & 63;
    int a   = ct * 16 + (l & 15);
    int kb  = ks * 32 + (l >> 4) * 8;
    const float* src = Wh + (size_t)a * HD_ + kb;
    float4 v0 = *(const float4*)(src);
    float4 v1 = *(const float4*)(src + 4);
    bf16x8 o;
    o[0] = (short)f2bf(v0.x); o[1] = (short)f2bf(v0.y);
    o[2] = (short)f2bf(v0.z); o[3] = (short)f2bf(v0.w);
    o[4] = (short)f2bf(v1.x); o[5] = (short)f2bf(v1.y);
    o[6] = (short)f2bf(v1.z); o[7] = (short)f2bf(v1.w);
    ((bf16x8*)whp)[g] = o;
}

// ---------------------------------------------------------------------------
// K1: 2 b's per block, 512 threads (8 waves).
__global__ __launch_bounds__(512) void k1_proj(
    const float* __restrict__ state, const float* __restrict__ Ws,
    const float* __restrict__ bs, const float* __restrict__ Wh,
    const float* __restrict__ bh,
    float* __restrict__ sn, float* __restrict__ qv, float* __restrict__ cv)
{
    __shared__ float st[2][SD_];
    __shared__ float spl[2][AD_];
    __shared__ float red[2][AD_];
    int tid = threadIdx.x, lane = tid & 63, w = tid >> 6;
    int b0 = blockIdx.x * 2;
    ((float4*)st)[tid] = ((const float4*)(state + (size_t)b0 * SD_))[tid];
    __syncthreads();
    float4 s0[4], s1[4];
    #pragma unroll
    for (int seg = 0; seg < 4; ++seg) {
        s0[seg] = *(const float4*)&st[0][seg * 256 + lane * 4];
        s1[seg] = *(const float4*)&st[1][seg * 256 + lane * 4];
    }
    #pragma unroll 2
    for (int i = 0; i < 32; ++i) {
        int a = w * 32 + i;
        const float4* wr = (const float4*)(Ws + (size_t)a * SD_);
        float p0 = 0.f, p1 = 0.f;
        #pragma unroll
        for (int seg = 0; seg < 4; ++seg) {
            float4 wv = wr[seg * 64 + lane];
            p0 += wv.x * s0[seg].x + wv.y * s0[seg].y + wv.z * s0[seg].z + wv.w * s0[seg].w;
            p1 += wv.x * s1[seg].x + wv.y * s1[seg].y + wv.z * s1[seg].z + wv.w * s1[seg].w;
        }
        #pragma unroll
        for (int d = 1; d < 64; d <<= 1) { p0 += __shfl_xor(p0, d); p1 += __shfl_xor(p1, d); }
        if (lane == 0) {
            float bsa = bs[a];
            spl[0][a] = p0 + bsa;
            spl[1][a] = p1 + bsa;
        }
    }
    __syncthreads();
    int tb = tid >> 8, t = tid & 255;
    float sv = spl[tb][t];
    red[tb][t] = sv * sv;
    __syncthreads();
    for (int s = 128; s > 0; s >>= 1) { if (t < s) red[tb][t] += red[tb][t + s]; __syncthreads(); }
    if (t == 0) sn[b0 + tb] = fmaxf(sqrtf(red[tb][0]), 1e-8f);
    __syncthreads();
    red[tb][t] = sv * bh[t];
    __syncthreads();
    for (int s = 128; s > 0; s >>= 1) { if (t < s) red[tb][t] += red[tb][t + s]; __syncthreads(); }
    if (t == 0) cv[b0 + tb] = red[tb][0];
    float q0 = 0.f, q1 = 0.f;
    #pragma unroll 8
    for (int a = 0; a < AD_; ++a) {
        float wv = Wh[(size_t)a * HD_ + tid];
        q0 += spl[0][a] * wv;
        q1 += spl[1][a] * wv;
    }
    qv[(size_t)b0 * HD_ + tid] = q0;
    qv[(size_t)(b0 + 1) * HD_ + tid] = q1;
}

// ---------------------------------------------------------------------------
// K2 fused: one block per b (512 threads, 8 waves), 2 blocks/CU.
// Coalesced staging: flat 16B index e = j*512+tid -> row=e>>5, cg=e&31
// (each wave load = contiguous 512B row segments, no L1 thrash).
__global__ __launch_bounds__(512, 4) void k2_fused(
    const float* __restrict__ hints, const unsigned short* __restrict__ whp,
    const float* __restrict__ qv, const float* __restrict__ cv,
    const float* __restrict__ sn, const float* __restrict__ bh,
    float* __restrict__ out)
{
    __shared__ __align__(16) char smem[76288];
    unsigned short* A_bf0 = (unsigned short*)smem;            // 32KB
    unsigned short* A_bf1 = (unsigned short*)(smem + 32768);  // 32KB
    float* q_lds   = (float*)(smem + 65536);                  // 2KB
    float* bh_lds  = (float*)(smem + 67584);                  // 1KB
    float* norm2p  = (float*)(smem + 68608);                  // 8x128 f32 = 4KB
    float* num_lds = (float*)(smem + 72704);                  // 512B
    float* sc      = (float*)(smem + 73216);                  // 1KB
    float* red     = (float*)(smem + 74240);                  // 1KB
    float* wsm     = (float*)(smem + 75264);                  // 1KB
    float* scratch = (float*)smem;                            // epilogue alias (8KB)

    int tid = threadIdx.x, lane = tid & 63, w = tid >> 6;
    int b = blockIdx.x;
    const float* hb = hints + (size_t)b * N_ * HD_;
    if (tid < 128) ((float4*)q_lds)[tid] = ((const float4*)(qv + (size_t)b * HD_))[tid];
    else if (tid < 192) ((float4*)bh_lds)[tid - 128] = ((const float4*)bh)[tid - 128];
    float cvb = cv[b];
    float snb = sn[b];
    int rr = tid >> 5;        // row sub-index (0..15)
    int cg = tid & 31;        // 16B col-group within 128-col chunk
    __syncthreads();

    for (int mc = 0; mc < 2; ++mc) {
        f32x4 acc[8][2];
        #pragma unroll
        for (int mf = 0; mf < 8; ++mf) {
            acc[mf][0] = (f32x4){0.f, 0.f, 0.f, 0.f};
            acc[mf][1] = (f32x4){0.f, 0.f, 0.f, 0.f};
        }
        float num_reg[8];
        #pragma unroll
        for (int j = 0; j < 8; ++j) num_reg[j] = 0.f;
        const float* hmc = hb + (size_t)(mc * 128 + rr) * HD_ + cg * 4;

        float4 v[8];
        // prologue: load+stage chunk 0
        #pragma unroll
        for (int j = 0; j < 8; ++j) v[j] = *(const float4*)(hmc + (size_t)j * 16 * HD_);
        {
            float4 qq = *(const float4*)(q_lds + cg * 4);
            #pragma unroll
            for (int j = 0; j < 8; ++j) {
                int row = j * 16 + rr;
                float4 x = v[j];
                num_reg[j] += x.x * qq.x + x.y * qq.y + x.z * qq.z + x.w * qq.w;
                ushort4 u;
                u.x = f2bf(x.x); u.y = f2bf(x.y); u.z = f2bf(x.z); u.w = f2bf(x.w);
                *(ushort4*)((char*)A_bf0 + row * 256 + ((cg * 8) ^ ((row & 7) << 4))) = u;
            }
        }
        __syncthreads();

        for (int kc = 0; kc < 4; ++kc) {
            // issue next chunk's loads early (T14: hide HBM under MFMA)
            if (kc < 3) {
                #pragma unroll
                for (int j = 0; j < 8; ++j)
                    v[j] = *(const float4*)(hmc + (size_t)j * 16 * HD_ + (kc + 1) * 128);
            }
            const unsigned short* Ab = (kc & 1) ? A_bf1 : A_bf0;
            int kc4 = kc * 4;
            #pragma unroll
            for (int ks = 0; ks < 4; ++ks) {
                bf16x8 bfr0 = ((const bf16x8*)whp)[((2 * w + 0) * 16 + kc4 + ks) * 64 + lane];
                bf16x8 bfr1 = ((const bf16x8*)whp)[((2 * w + 1) * 16 + kc4 + ks) * 64 + lane];
                #pragma unroll
                for (int mf = 0; mf < 8; ++mf) {
                    int r = mf * 16 + (lane & 15);
                    bf16x8 afr = *(const bf16x8*)((const char*)Ab + r * 256 +
                                 ((ks * 64 + (lane >> 4) * 16) ^ ((r & 7) << 4)));
                    acc[mf][0] = __builtin_amdgcn_mfma_f32_16x16x32_bf16(afr, bfr0, acc[mf][0], 0, 0, 0);
                    acc[mf][1] = __builtin_amdgcn_mfma_f32_16x16x32_bf16(afr, bfr1, acc[mf][1], 0, 0, 0);
                }
            }
            if (kc < 3) {
                unsigned short* Aw = (kc & 1) ? A_bf0 : A_bf1;
                float4 qq = *(const float4*)(q_lds + (kc + 1) * 128 + cg * 4);
                #pragma unroll
                for (int j = 0; j < 8; ++j) {
                    int row = j * 16 + rr;
                    float4 x = v[j];
                    num_reg[j] += x.x * qq.x + x.y * qq.y + x.z * qq.z + x.w * qq.w;
                    ushort4 u;
                    u.x = f2bf(x.x); u.y = f2bf(x.y); u.z = f2bf(x.z); u.w = f2bf(x.w);
                    *(ushort4*)((char*)Aw + row * 256 + ((cg * 8) ^ ((row & 7) << 4))) = u;
                }
            }
            __syncthreads();
        }

        // num: reduce 32 lanes (same row) -> num_lds[row]
        #pragma unroll
        for (int j = 0; j < 8; ++j) {
            float nv = num_reg[j];
            nv += __shfl_xor(nv, 1); nv += __shfl_xor(nv, 2); nv += __shfl_xor(nv, 4);
            nv += __shfl_xor(nv, 8); nv += __shfl_xor(nv, 16);
            if ((tid & 31) == 0) num_lds[j * 16 + rr] = nv;
        }

        // norm: C layout col = ct*16+(lane&15), row = mf*16+(lane>>4)*4+r
        int q4l = lane >> 4;
        float bh0 = bh_lds[(2 * w + 0) * 16 + (lane & 15)];
        float bh1 = bh_lds[(2 * w + 1) * 16 + (lane & 15)];
        #pragma unroll
        for (int mf = 0; mf < 8; ++mf) {
            #pragma unroll
            for (int r = 0; r < 4; ++r) {
                float h0 = acc[mf][0][r] + bh0;
                float h1 = acc[mf][1][r] + bh1;
                float vv = h0 * h0 + h1 * h1;
                vv += __shfl_xor(vv, 1); vv += __shfl_xor(vv, 2);
                vv += __shfl_xor(vv, 4); vv += __shfl_xor(vv, 8);
                if ((lane & 15) == 0) norm2p[w * 128 + mf * 16 + q4l * 4 + r] = vv;
            }
        }
        __syncthreads();
        if (tid < 128) {
            float n2 = 0.f;
            #pragma unroll
            for (int ww = 0; ww < 8; ++ww) n2 += norm2p[ww * 128 + tid];
            float hn = fmaxf(sqrtf(n2), 1e-8f);
            sc[mc * 128 + tid] = (num_lds[tid] + cvb) / (snb * hn);
        }
        __syncthreads();
    }

    // softmax over sc[256]
    if (tid < 256) red[tid] = sc[tid];
    __syncthreads();
    for (int s = 128; s > 0; s >>= 1) { if (tid < s) red[tid] = fmaxf(red[tid], red[tid + s]); __syncthreads(); }
    float mx = red[0];
    __syncthreads();
    if (tid < 256) { float e = __expf(sc[tid] - mx); sc[tid] = e; red[tid] = e; }
    __syncthreads();
    for (int s = 128; s > 0; s >>= 1) { if (tid < s) red[tid] += red[tid + s]; __syncthreads(); }
    float inv = 1.f / red[0];
    __syncthreads();
    if (tid < 256) wsm[tid] = sc[tid] * inv;
    __syncthreads();

    // weighted sum (vectorized): 4 n-groups x 128 h-groups, then LDS combine
    int hg = tid & 127, ng = tid >> 7;
    const float* hbe = hb + (size_t)(ng * 64) * HD_ + hg * 4;
    float ax = 0.f, ay = 0.f, az = 0.f, aw = 0.f;
    #pragma unroll 8
    for (int n = 0; n < 64; ++n) {
        float4 hv = *(const float4*)(hbe + (size_t)n * HD_);
        float wn = wsm[ng * 64 + n];
        ax += wn * hv.x; ay += wn * hv.y; az += wn * hv.z; aw += wn * hv.w;
    }
    *(float4*)(scratch + ng * 512 + hg * 4) = (float4){ax, ay, az, aw};
    __syncthreads();
    out[(size_t)b * HD_ + tid] =
        scratch[tid] + scratch[512 + tid] + scratch[1024 + tid] + scratch[1536 + tid];
}

// ---------------------------------------------------------------------------
extern "C" void kernel_launch(void* const* d_in, const int* in_sizes, int n_in,
                              void* d_out, int out_size, void* d_ws, size_t ws_size,
                              hipStream_t stream) {
    const float* state = (const float*)d_in[0];
    const float* hints = (const float*)d_in[1];
    const float* Ws    = (const float*)d_in[2];
    const float* bs    = (const float*)d_in[3];
    const float* Wh    = (const float*)d_in[4];
    const float* bh    = (const float*)d_in[5];
    float* out = (float*)d_out;

    float* sn = (float*)d_ws;                          // B
    float* cv = sn + B_;                               // B
    float* qv = cv + B_;                               // B*HD
    unsigned short* whp = (unsigned short*)(qv + (size_t)B_ * HD_);  // AD*HD bf16

    k0_pack<<<64, 256, 0, stream>>>(Wh, whp);
    k1_proj<<<B_ / 2, 512, 0, stream>>>(state, Ws, bs, Wh, bh, sn, qv, cv);
    k2_fused<<<B_, 512, 0, stream>>>(hints, whp, qv, cv, sn, bh, out);
}

// Round 4
// 237.499 us; speedup vs baseline: 1.4875x; 1.4875x over previous
//
#include <hip/hip_runtime.h>
#include <hip/hip_bf16.h>

typedef __attribute__((ext_vector_type(8))) short bf16x8;
typedef __attribute__((ext_vector_type(4))) float f32x4;

#define B_  512
#define N_  256
#define SD_ 1024
#define HD_ 512
#define AD_ 256

__device__ __forceinline__ unsigned short f2bf(float f) {
    unsigned int u = __float_as_uint(f);
    unsigned int r = (u + 0x7FFFu + ((u >> 16) & 1u)) >> 16;
    return (unsigned short)r;
}

// ---------------------------------------------------------------------------
// K0: pack Wh (AD x HD, f32, row-major) into bf16 B-fragment layout for
// mfma_f32_16x16x32_bf16. Fragment (ct, ks): 64 lanes x 8 bf16 contiguous.
// B[k][col] = Wh[col][k];  col = ct*16 + (lane&15), k = ks*32 + (lane>>4)*8 + i
__global__ void k0_pack(const float* __restrict__ Wh, unsigned short* __restrict__ whp) {
    int g = blockIdx.x * 256 + threadIdx.x;   // 16384 fragment-lanes total
    int ct  = g >> 10;
    int rem = g & 1023;
    int ks  = rem >> 6;
    int l   = rem & 63;
    int a   = ct * 16 + (l & 15);
    int kb  = ks * 32 + (l >> 4) * 8;
    const float* src = Wh + (size_t)a * HD_ + kb;
    float4 v0 = *(const float4*)(src);
    float4 v1 = *(const float4*)(src + 4);
    bf16x8 o;
    o[0] = (short)f2bf(v0.x); o[1] = (short)f2bf(v0.y);
    o[2] = (short)f2bf(v0.z); o[3] = (short)f2bf(v0.w);
    o[4] = (short)f2bf(v1.x); o[5] = (short)f2bf(v1.y);
    o[6] = (short)f2bf(v1.z); o[7] = (short)f2bf(v1.w);
    ((bf16x8*)whp)[g] = o;
}

// ---------------------------------------------------------------------------
// K1: 2 b's per block, 512 threads (8 waves).
__global__ __launch_bounds__(512) void k1_proj(
    const float* __restrict__ state, const float* __restrict__ Ws,
    const float* __restrict__ bs, const float* __restrict__ Wh,
    const float* __restrict__ bh,
    float* __restrict__ sn, float* __restrict__ qv, float* __restrict__ cv)
{
    __shared__ float st[2][SD_];
    __shared__ float spl[2][AD_];
    __shared__ float red[2][AD_];
    int tid = threadIdx.x, lane = tid & 63, w = tid >> 6;
    int b0 = blockIdx.x * 2;
    ((float4*)st)[tid] = ((const float4*)(state + (size_t)b0 * SD_))[tid];
    __syncthreads();
    float4 s0[4], s1[4];
    #pragma unroll
    for (int seg = 0; seg < 4; ++seg) {
        s0[seg] = *(const float4*)&st[0][seg * 256 + lane * 4];
        s1[seg] = *(const float4*)&st[1][seg * 256 + lane * 4];
    }
    #pragma unroll 2
    for (int i = 0; i < 32; ++i) {
        int a = w * 32 + i;
        const float4* wr = (const float4*)(Ws + (size_t)a * SD_);
        float p0 = 0.f, p1 = 0.f;
        #pragma unroll
        for (int seg = 0; seg < 4; ++seg) {
            float4 wv = wr[seg * 64 + lane];
            p0 += wv.x * s0[seg].x + wv.y * s0[seg].y + wv.z * s0[seg].z + wv.w * s0[seg].w;
            p1 += wv.x * s1[seg].x + wv.y * s1[seg].y + wv.z * s1[seg].z + wv.w * s1[seg].w;
        }
        #pragma unroll
        for (int d = 1; d < 64; d <<= 1) { p0 += __shfl_xor(p0, d); p1 += __shfl_xor(p1, d); }
        if (lane == 0) {
            float bsa = bs[a];
            spl[0][a] = p0 + bsa;
            spl[1][a] = p1 + bsa;
        }
    }
    __syncthreads();
    int tb = tid >> 8, t = tid & 255;
    float sv = spl[tb][t];
    red[tb][t] = sv * sv;
    __syncthreads();
    for (int s = 128; s > 0; s >>= 1) { if (t < s) red[tb][t] += red[tb][t + s]; __syncthreads(); }
    if (t == 0) sn[b0 + tb] = fmaxf(sqrtf(red[tb][0]), 1e-8f);
    __syncthreads();
    red[tb][t] = sv * bh[t];
    __syncthreads();
    for (int s = 128; s > 0; s >>= 1) { if (t < s) red[tb][t] += red[tb][t + s]; __syncthreads(); }
    if (t == 0) cv[b0 + tb] = red[tb][0];
    float q0 = 0.f, q1 = 0.f;
    #pragma unroll 8
    for (int a = 0; a < AD_; ++a) {
        float wv = Wh[(size_t)a * HD_ + tid];
        q0 += spl[0][a] * wv;
        q1 += spl[1][a] * wv;
    }
    qv[(size_t)b0 * HD_ + tid] = q0;
    qv[(size_t)(b0 + 1) * HD_ + tid] = q1;
}

// ---------------------------------------------------------------------------
// K2 fused: one block per b (512 threads, 8 waves), 2 blocks/CU (128 VGPR —
// (512,2): do NOT raise min-waves; (512,4) forced 64 VGPR and spilled, R3).
// Coalesced staging: flat 16B index e = j*512+tid -> row=e>>5, cg=e&31
// (each wave load = two contiguous 512B row segments, no L1 thrash).
__global__ __launch_bounds__(512, 2) void k2_fused(
    const float* __restrict__ hints, const unsigned short* __restrict__ whp,
    const float* __restrict__ qv, const float* __restrict__ cv,
    const float* __restrict__ sn, const float* __restrict__ bh,
    float* __restrict__ out)
{
    __shared__ __align__(16) char smem[76288];
    unsigned short* A_bf0 = (unsigned short*)smem;            // 32KB
    unsigned short* A_bf1 = (unsigned short*)(smem + 32768);  // 32KB
    float* q_lds   = (float*)(smem + 65536);                  // 2KB
    float* bh_lds  = (float*)(smem + 67584);                  // 1KB
    float* norm2p  = (float*)(smem + 68608);                  // 8x128 f32 = 4KB
    float* num_lds = (float*)(smem + 72704);                  // 512B
    float* sc      = (float*)(smem + 73216);                  // 1KB
    float* red     = (float*)(smem + 74240);                  // 1KB
    float* wsm     = (float*)(smem + 75264);                  // 1KB
    float* scratch = (float*)smem;                            // epilogue alias (8KB)

    int tid = threadIdx.x, lane = tid & 63, w = tid >> 6;
    int b = blockIdx.x;
    const float* hb = hints + (size_t)b * N_ * HD_;
    if (tid < 128) ((float4*)q_lds)[tid] = ((const float4*)(qv + (size_t)b * HD_))[tid];
    else if (tid < 192) ((float4*)bh_lds)[tid - 128] = ((const float4*)bh)[tid - 128];
    float cvb = cv[b];
    float snb = sn[b];
    int rr = tid >> 5;        // row sub-index (0..15)
    int cg = tid & 31;        // 16B col-group within 128-col chunk
    __syncthreads();

    for (int mc = 0; mc < 2; ++mc) {
        f32x4 acc[8][2];
        #pragma unroll
        for (int mf = 0; mf < 8; ++mf) {
            acc[mf][0] = (f32x4){0.f, 0.f, 0.f, 0.f};
            acc[mf][1] = (f32x4){0.f, 0.f, 0.f, 0.f};
        }
        float num_reg[8];
        #pragma unroll
        for (int j = 0; j < 8; ++j) num_reg[j] = 0.f;
        const float* hmc = hb + (size_t)(mc * 128 + rr) * HD_ + cg * 4;

        float4 v[8];
        // prologue: load+stage chunk 0
        #pragma unroll
        for (int j = 0; j < 8; ++j) v[j] = *(const float4*)(hmc + (size_t)j * 16 * HD_);
        {
            float4 qq = *(const float4*)(q_lds + cg * 4);
            #pragma unroll
            for (int j = 0; j < 8; ++j) {
                int row = j * 16 + rr;
                float4 x = v[j];
                num_reg[j] += x.x * qq.x + x.y * qq.y + x.z * qq.z + x.w * qq.w;
                ushort4 u;
                u.x = f2bf(x.x); u.y = f2bf(x.y); u.z = f2bf(x.z); u.w = f2bf(x.w);
                *(ushort4*)((char*)A_bf0 + row * 256 + ((cg * 8) ^ ((row & 7) << 4))) = u;
            }
        }
        __syncthreads();

        for (int kc = 0; kc < 4; ++kc) {
            // issue next chunk's loads early (T14: hide HBM under MFMA)
            if (kc < 3) {
                #pragma unroll
                for (int j = 0; j < 8; ++j)
                    v[j] = *(const float4*)(hmc + (size_t)j * 16 * HD_ + (kc + 1) * 128);
            }
            const unsigned short* Ab = (kc & 1) ? A_bf1 : A_bf0;
            int kc4 = kc * 4;
            #pragma unroll
            for (int ks = 0; ks < 4; ++ks) {
                bf16x8 bfr0 = ((const bf16x8*)whp)[((2 * w + 0) * 16 + kc4 + ks) * 64 + lane];
                bf16x8 bfr1 = ((const bf16x8*)whp)[((2 * w + 1) * 16 + kc4 + ks) * 64 + lane];
                #pragma unroll
                for (int mf = 0; mf < 8; ++mf) {
                    int r = mf * 16 + (lane & 15);
                    bf16x8 afr = *(const bf16x8*)((const char*)Ab + r * 256 +
                                 ((ks * 64 + (lane >> 4) * 16) ^ ((r & 7) << 4)));
                    acc[mf][0] = __builtin_amdgcn_mfma_f32_16x16x32_bf16(afr, bfr0, acc[mf][0], 0, 0, 0);
                    acc[mf][1] = __builtin_amdgcn_mfma_f32_16x16x32_bf16(afr, bfr1, acc[mf][1], 0, 0, 0);
                }
            }
            if (kc < 3) {
                unsigned short* Aw = (kc & 1) ? A_bf0 : A_bf1;
                float4 qq = *(const float4*)(q_lds + (kc + 1) * 128 + cg * 4);
                #pragma unroll
                for (int j = 0; j < 8; ++j) {
                    int row = j * 16 + rr;
                    float4 x = v[j];
                    num_reg[j] += x.x * qq.x + x.y * qq.y + x.z * qq.z + x.w * qq.w;
                    ushort4 u;
                    u.x = f2bf(x.x); u.y = f2bf(x.y); u.z = f2bf(x.z); u.w = f2bf(x.w);
                    *(ushort4*)((char*)Aw + row * 256 + ((cg * 8) ^ ((row & 7) << 4))) = u;
                }
            }
            __syncthreads();
        }

        // num: reduce 32 lanes (same row) -> num_lds[row]
        #pragma unroll
        for (int j = 0; j < 8; ++j) {
            float nv = num_reg[j];
            nv += __shfl_xor(nv, 1); nv += __shfl_xor(nv, 2); nv += __shfl_xor(nv, 4);
            nv += __shfl_xor(nv, 8); nv += __shfl_xor(nv, 16);
            if ((tid & 31) == 0) num_lds[j * 16 + rr] = nv;
        }

        // norm: C layout col = ct*16+(lane&15), row = mf*16+(lane>>4)*4+r
        int q4l = lane >> 4;
        float bh0 = bh_lds[(2 * w + 0) * 16 + (lane & 15)];
        float bh1 = bh_lds[(2 * w + 1) * 16 + (lane & 15)];
        #pragma unroll
        for (int mf = 0; mf < 8; ++mf) {
            #pragma unroll
            for (int r = 0; r < 4; ++r) {
                float h0 = acc[mf][0][r] + bh0;
                float h1 = acc[mf][1][r] + bh1;
                float vv = h0 * h0 + h1 * h1;
                vv += __shfl_xor(vv, 1); vv += __shfl_xor(vv, 2);
                vv += __shfl_xor(vv, 4); vv += __shfl_xor(vv, 8);
                if ((lane & 15) == 0) norm2p[w * 128 + mf * 16 + q4l * 4 + r] = vv;
            }
        }
        __syncthreads();
        if (tid < 128) {
            float n2 = 0.f;
            #pragma unroll
            for (int ww = 0; ww < 8; ++ww) n2 += norm2p[ww * 128 + tid];
            float hn = fmaxf(sqrtf(n2), 1e-8f);
            sc[mc * 128 + tid] = (num_lds[tid] + cvb) / (snb * hn);
        }
        __syncthreads();
    }

    // softmax over sc[256]
    if (tid < 256) red[tid] = sc[tid];
    __syncthreads();
    for (int s = 128; s > 0; s >>= 1) { if (tid < s) red[tid] = fmaxf(red[tid], red[tid + s]); __syncthreads(); }
    float mx = red[0];
    __syncthreads();
    if (tid < 256) { float e = __expf(sc[tid] - mx); sc[tid] = e; red[tid] = e; }
    __syncthreads();
    for (int s = 128; s > 0; s >>= 1) { if (tid < s) red[tid] += red[tid + s]; __syncthreads(); }
    float inv = 1.f / red[0];
    __syncthreads();
    if (tid < 256) wsm[tid] = sc[tid] * inv;
    __syncthreads();

    // weighted sum (vectorized): 4 n-groups x 128 h-groups, then LDS combine
    int hg = tid & 127, ng = tid >> 7;
    const float* hbe = hb + (size_t)(ng * 64) * HD_ + hg * 4;
    float ax = 0.f, ay = 0.f, az = 0.f, aw = 0.f;
    #pragma unroll 8
    for (int n = 0; n < 64; ++n) {
        float4 hv = *(const float4*)(hbe + (size_t)n * HD_);
        float wn = wsm[ng * 64 + n];
        ax += wn * hv.x; ay += wn * hv.y; az += wn * hv.z; aw += wn * hv.w;
    }
    *(float4*)(scratch + ng * 512 + hg * 4) = (float4){ax, ay, az, aw};
    __syncthreads();
    out[(size_t)b * HD_ + tid] =
        scratch[tid] + scratch[512 + tid] + scratch[1024 + tid] + scratch[1536 + tid];
}

// ---------------------------------------------------------------------------
extern "C" void kernel_launch(void* const* d_in, const int* in_sizes, int n_in,
                              void* d_out, int out_size, void* d_ws, size_t ws_size,
                              hipStream_t stream) {
    const float* state = (const float*)d_in[0];
    const float* hints = (const float*)d_in[1];
    const float* Ws    = (const float*)d_in[2];
    const float* bs    = (const float*)d_in[3];
    const float* Wh    = (const float*)d_in[4];
    const float* bh    = (const float*)d_in[5];
    float* out = (float*)d_out;

    float* sn = (float*)d_ws;                          // B
    float* cv = sn + B_;                               // B
    float* qv = cv + B_;                               // B*HD
    unsigned short* whp = (unsigned short*)(qv + (size_t)B_ * HD_);  // AD*HD bf16

    k0_pack<<<64, 256, 0, stream>>>(Wh, whp);
    k1_proj<<<B_ / 2, 512, 0, stream>>>(state, Ws, bs, Wh, bh, sn, qv, cv);
    k2_fused<<<B_, 512, 0, stream>>>(hints, whp, qv, cv, sn, bh, out);
}